// Round 5
// baseline (108.394 us; speedup 1.0000x reference)
//
#include <hip/hip_runtime.h>
#include <hip/hip_bf16.h>

#define N 8192
#define D 128
#define JC 32                // j-chunks (grid parallelism over j)
#define BM 128               // rows per block (4 waves x 32 rows)
#define NRB (N / BM)         // 64 row-blocks
#define JCH (N / JC)         // 256 columns per chunk
#define NLBL 100             // labels are in [0, 100)
#define LCH 128              // label-sum blocks (= fused_prep blocks)
#define LR 64                // rows per fused_prep block

#define K1F 14.426950408889634f    // 10 * log2(e)
#define K0F (-14.426950408889634f)

#if __has_builtin(__builtin_amdgcn_exp2f)
#define EXP2(x) __builtin_amdgcn_exp2f(x)
#else
#define EXP2(x) exp2f(x)
#endif

typedef __attribute__((ext_vector_type(8))) short bf16x8;
typedef __attribute__((ext_vector_type(4))) float f32x4;

// ---------------- Stage 0 (fused): normalize -> zn/dii, then label sums ------
// 128 blocks x 64 rows. Phase 1: 4 waves x 16 rows, normalize, write zn global
// + stash bf16 row in LDS. Phase 2: 2 halves x 128 dims accumulate per-label
// sums from LDS (thread-exclusive column -> deterministic).
__global__ __launch_bounds__(256) void fused_prep(const float* __restrict__ z,
                                                  const int* __restrict__ y,
                                                  ushort* __restrict__ zn,
                                                  float* __restrict__ dii,
                                                  float* __restrict__ tpart,
                                                  float* __restrict__ cpart) {
    __shared__ ushort znl[LR][D];      // 16 KB
    __shared__ float  tl[2][NLBL][D];  // 100 KB
    __shared__ float  ch[2][128];
    __shared__ int    ly[LR];
    const int wid  = threadIdx.x >> 6;
    const int lane = threadIdx.x & 63;
    const int r0   = blockIdx.x * LR;
    if (threadIdx.x < LR) ly[threadIdx.x] = y[r0 + threadIdx.x];

    // Phase 1: normalize 16 rows per wave
    for (int k = 0; k < 16; ++k) {
        const int row = wid * 16 + k;
        const float2 v = reinterpret_cast<const float2*>(z + (size_t)(r0 + row) * D)[lane];
        float ss = v.x * v.x + v.y * v.y;
        #pragma unroll
        for (int m = 1; m < 64; m <<= 1) ss += __shfl_xor(ss, m);
        const float inv = 1.0f / fmaxf(sqrtf(ss), 1e-8f);
        __hip_bfloat16 b0 = __float2bfloat16(v.x * inv);
        __hip_bfloat16 b1 = __float2bfloat16(v.y * inv);
        ushort2 o;
        o.x = *reinterpret_cast<ushort*>(&b0);
        o.y = *reinterpret_cast<ushort*>(&b1);
        reinterpret_cast<ushort2*>(zn + (size_t)(r0 + row) * D)[lane] = o;
        *reinterpret_cast<ushort2*>(&znl[row][lane * 2]) = o;
        // self-dot of the ROUNDED vector (subtracted from S and Z later)
        const float f0 = __bfloat162float(b0), f1 = __bfloat162float(b1);
        float s2 = f0 * f0 + f1 * f1;
        #pragma unroll
        for (int m = 1; m < 64; m <<= 1) s2 += __shfl_xor(s2, m);
        if (lane == 0) dii[r0 + row] = s2;
    }
    __syncthreads();

    // Phase 2: label sums, 2 halves x 32 rows serial, thread-exclusive dim
    const int h = threadIdx.x >> 7;
    const int d = threadIdx.x & 127;
    for (int c = 0; c < NLBL; ++c) tl[h][c][d] = 0.0f;
    float cl = 0.0f;
    for (int j = 0; j < 32; ++j) {
        const int jr = h * 32 + j;
        const int c  = ly[jr];
        __hip_bfloat16 hb;
        *reinterpret_cast<ushort*>(&hb) = znl[jr][d];
        tl[h][c][d] += __bfloat162float(hb);      // exclusive column: no race
        cl += (c == d) ? 1.0f : 0.0f;
    }
    ch[h][d] = cl;
    __syncthreads();
    const float* t0 = &tl[0][0][0];
    for (int idx = threadIdx.x; idx < NLBL * D; idx += 256)
        tpart[(size_t)blockIdx.x * NLBL * D + idx] = t0[idx] + t0[NLBL * D + idx];
    if (threadIdx.x < NLBL)
        cpart[blockIdx.x * NLBL + threadIdx.x] = ch[0][threadIdx.x] + ch[1][threadIdx.x];
}

__global__ __launch_bounds__(256) void reduce_t_kernel(const float* __restrict__ tpart,
                                                       const float* __restrict__ cpart,
                                                       float* __restrict__ t,
                                                       float* __restrict__ cnt) {
    const int idx = blockIdx.x * 256 + threadIdx.x;
    if (idx < NLBL * D) {
        float s0 = 0.f, s1 = 0.f, s2 = 0.f, s3 = 0.f;
        #pragma unroll 4
        for (int b = 0; b < LCH; b += 4) {
            s0 += tpart[(size_t)(b + 0) * NLBL * D + idx];
            s1 += tpart[(size_t)(b + 1) * NLBL * D + idx];
            s2 += tpart[(size_t)(b + 2) * NLBL * D + idx];
            s3 += tpart[(size_t)(b + 3) * NLBL * D + idx];
        }
        t[idx] = (s0 + s1) + (s2 + s3);
    }
    if (idx < NLBL) {
        float s = 0.0f;
        for (int b = 0; b < LCH; ++b) s += cpart[b * NLBL + idx];
        cnt[idx] = s;
    }
}

// ---------------- Stage 1: streaming MFMA, Z-only epilogue ----------------
// 4 waves/block share the SAME 16-col B slice per iteration (L1 dedup);
// each wave owns a private 32-row A-tile -> ~100 regs/wave, 4 blocks/CU.
// No LDS, no barriers: waves are fully independent.
__global__ __launch_bounds__(256, 4) void supcon_main(const ushort* __restrict__ zn,
                                                      float* __restrict__ pZ) {
    const int wid  = threadIdx.x >> 6;
    const int lane = threadIdx.x & 63;
    const int g    = lane >> 4;      // 0..3 lane group
    const int lj   = lane & 15;      // col within tile / row within A-frag
    const int rowBlk = blockIdx.x % NRB;
    const int chunk  = blockIdx.x / NRB;
    const int rowBase = rowBlk * BM + wid * 32;   // this wave's 32 rows

    // B column stream: 16 cols per iteration, shared by all 4 waves
    const ushort* jp = zn + (size_t)(chunk * JCH + lj) * D + g * 8;

    bf16x8 b0[4], b1[4];
    #pragma unroll
    for (int s = 0; s < 4; ++s) b0[s] = *reinterpret_cast<const bf16x8*>(jp + s * 32);

    // A fragments: 2 M-tiles x 4 K-steps (lane row = lj)
    bf16x8 a[2][4];
    #pragma unroll
    for (int m = 0; m < 2; ++m) {
        const ushort* rp = zn + (size_t)(rowBase + m * 16 + lj) * D;
        #pragma unroll
        for (int s = 0; s < 4; ++s)
            a[m][s] = *reinterpret_cast<const bf16x8*>(rp + s * 32 + g * 8);
    }

    float Z[2][4];
    #pragma unroll
    for (int m = 0; m < 2; ++m)
        #pragma unroll
        for (int r = 0; r < 4; ++r) Z[m][r] = 0.0f;

    const f32x4 zero4 = {0.f, 0.f, 0.f, 0.f};
    auto compute = [&](const bf16x8* B) {
        #pragma unroll
        for (int m = 0; m < 2; ++m) {
            f32x4 acc = zero4;
            #pragma unroll
            for (int s = 0; s < 4; ++s)
                acc = __builtin_amdgcn_mfma_f32_16x16x32_bf16(a[m][s], B[s], acc, 0, 0, 0);
            #pragma unroll
            for (int r = 0; r < 4; ++r)
                Z[m][r] += EXP2(fmaf(acc[r], K1F, K0F));   // exp(10*dot - 10)
        }
    };

    const int NIT = JCH / 16;        // 16 iterations, 16 cols each
    #pragma unroll 1
    for (int it = 0; it < NIT; it += 2) {
        const ushort* jp1 = jp + 16 * D;             // tile it+1
        #pragma unroll
        for (int s = 0; s < 4; ++s) b1[s] = *reinterpret_cast<const bf16x8*>(jp1 + s * 32);
        compute(b0);
        if (it + 2 < NIT) {
            const ushort* jp2 = jp + 32 * D;         // tile it+2
            #pragma unroll
            for (int s = 0; s < 4; ++s) b0[s] = *reinterpret_cast<const bf16x8*>(jp2 + s * 32);
        }
        compute(b1);
        jp += 32 * D;
    }

    // Sum the 16 cols of each tile (within 16-lane groups)
    #pragma unroll
    for (int m = 0; m < 2; ++m)
        #pragma unroll
        for (int r = 0; r < 4; ++r)
            #pragma unroll
            for (int mk = 1; mk < 16; mk <<= 1)
                Z[m][r] += __shfl_xor(Z[m][r], mk);

    // Each row owned by exactly one wave -> direct write, no LDS combine
    if (lj == 0) {
        #pragma unroll
        for (int m = 0; m < 2; ++m)
            #pragma unroll
            for (int r = 0; r < 4; ++r)
                pZ[chunk * N + rowBase + m * 16 + g * 4 + r] = Z[m][r];
    }
}

// ---------------- Stage 2: finalize loss ----------------
__global__ __launch_bounds__(256) void supcon_finalize(const ushort* __restrict__ zn,
                                                       const int* __restrict__ y,
                                                       const float* __restrict__ pZ,
                                                       const float* __restrict__ dii,
                                                       const float* __restrict__ t,
                                                       const float* __restrict__ cnt,
                                                       float* __restrict__ out) {
    const int wid  = threadIdx.x >> 6;
    const int lane = threadIdx.x & 63;
    const int row  = blockIdx.x * 4 + wid;
    const int c    = y[row];
    const ushort2 u = reinterpret_cast<const ushort2*>(zn + (size_t)row * D)[lane];
    const float2 tv = reinterpret_cast<const float2*>(t + (size_t)c * D)[lane];
    __hip_bfloat16 h0, h1;
    *reinterpret_cast<ushort*>(&h0) = u.x;
    *reinterpret_cast<ushort*>(&h1) = u.y;
    float dot = __bfloat162float(h0) * tv.x + __bfloat162float(h1) * tv.y;
    #pragma unroll
    for (int m = 1; m < 64; m <<= 1) dot += __shfl_xor(dot, m);
    // 32 j-chunk partials read wave-parallel
    float zs = (lane < JC) ? pZ[lane * N + row] : 0.0f;
    #pragma unroll
    for (int m = 16; m >= 1; m >>= 1) zs += __shfl_xor(zs, m);
    if (lane == 0) {
        const float di = dii[row];
        const float zc = zs - EXP2(fmaf(di, K1F, K0F));   // remove self term
        const float cn = cnt[c] - 1.0f;                   // exclude self
        const float S  = dot - di;                        // exclude self
        const float denom = fmaxf(cn, 1.0f);
        const float lse   = 10.0f + logf(zc);
        out[row] = -(10.0f * S) / denom + (cn > 0.5f ? lse : 0.0f);
    }
}

extern "C" void kernel_launch(void* const* d_in, const int* in_sizes, int n_in,
                              void* d_out, int out_size, void* d_ws, size_t ws_size,
                              hipStream_t stream) {
    const float* z = (const float*)d_in[0];
    const int*   y = (const int*)d_in[1];
    float* out = (float*)d_out;

    // ws layout (~9.8 MB total)
    ushort* zn    = (ushort*)d_ws;                                  // 2 MB
    float*  dii   = (float*)((char*)d_ws + (size_t)N * D * 2);      // 32 KB
    float*  tpart = dii + N;                                        // 6.55 MB
    float*  cpart = tpart + (size_t)LCH * NLBL * D;                 // 51.2 KB
    float*  t     = cpart + (size_t)LCH * NLBL;                     // 51.2 KB
    float*  cnt   = t + (size_t)NLBL * D;                           // 400 B
    float*  pZ    = cnt + NLBL;                                     // 1 MB

    fused_prep<<<LCH, 256, 0, stream>>>(z, y, zn, dii, tpart, cpart);
    supcon_main<<<NRB * JC, 256, 0, stream>>>(zn, pZ);
    reduce_t_kernel<<<(NLBL * D + 255) / 256, 256, 0, stream>>>(tpart, cpart, t, cnt);
    supcon_finalize<<<N / 4, 256, 0, stream>>>(zn, y, pZ, dii, t, cnt, out);
}